// Round 9
// baseline (75.674 us; speedup 1.0000x reference)
//
#include <hip/hip_runtime.h>
#include <hip/hip_bf16.h>

#define NB 4
#define NL 1024
#define NH 16
#define ND 1024
#define HD 64
#define FMIN_F32 (-3.4028234663852886e38f)
#define LOG2E 1.4426950408889634f

typedef __bf16 bf16x8 __attribute__((ext_vector_type(8)));
typedef float f32x4 __attribute__((ext_vector_type(4)));
typedef unsigned int u32;

static __device__ inline unsigned short f2bf(float f) {
    __hip_bfloat16 h = __float2bfloat16(f);
    return __builtin_bit_cast(unsigned short, h);
}

// split f32 into bf16 hi + bf16 lo (x ~= hi + lo, error ~2^-18 rel)
static __device__ inline void bfsplit(float x, unsigned short& hi, unsigned short& lo) {
    unsigned u = __builtin_bit_cast(unsigned, x);
    unsigned r = (u + 0x7FFFu + ((u >> 16) & 1u)) >> 16;
    hi = (unsigned short)r;
    float hf = __builtin_bit_cast(float, r << 16);
    lo = f2bf(x - hf);
}

static __device__ inline u32 pk2(unsigned short a, unsigned short b) {
    return (u32)a | ((u32)b << 16);
}

// async global->LDS, 16B per lane. LDS dest = firstlane(lds)+lane*16.
static __device__ __forceinline__ void gload16(void* lds, const void* g) {
    __builtin_amdgcn_global_load_lds(
        (const __attribute__((address_space(1))) u32*)g,
        (__attribute__((address_space(3))) u32*)lds, 16, 0, 0);
}

// ---------------------------------------------------------------------------
// Kernel 1: row sums of query/key/value.
// ---------------------------------------------------------------------------
__global__ __launch_bounds__(256)
void rowsum_kernel(const float* __restrict__ q, const float* __restrict__ k,
                   const float* __restrict__ v, float* __restrict__ out) {
    int gw   = blockIdx.x * 4 + (threadIdx.x >> 6);
    int lane = threadIdx.x & 63;
    int tensor = gw >> 12;
    int row    = gw & 4095;
    const float* src = tensor == 0 ? q : (tensor == 1 ? k : v);
    const float* p = src + (size_t)row * ND;
    float s = 0.f;
#pragma unroll
    for (int t = 0; t < 4; ++t) {
        float4 x = *reinterpret_cast<const float4*>(p + t * 256 + lane * 4);
        s += (x.x + x.y) + (x.z + x.w);
    }
#pragma unroll
    for (int off = 32; off; off >>= 1) s += __shfl_xor(s, off);
    if (lane == 0) out[tensor * (NB * NL) + row] = s;
}

// ---------------------------------------------------------------------------
// Kernel 2: prep — pre-swizzled operand tiles + per-tile S sums + per-j tables.
//  [0,256):   k_w -> kPhi/kPlo   [256,512): v_w -> vP + S
//  [512,640): o_w -> BP          [640,656): ksg/vsg/pmi per-j tables
// ---------------------------------------------------------------------------
__global__ __launch_bounds__(256)
void prep_kernel(const float* __restrict__ k_w, const float* __restrict__ v_w,
                 const float* __restrict__ o_w, const float* __restrict__ sums,
                 const int* __restrict__ pad,
                 unsigned short* __restrict__ kPhi, unsigned short* __restrict__ kPlo,
                 unsigned short* __restrict__ vP, unsigned short* __restrict__ BP,
                 float* __restrict__ S, float* __restrict__ ksg,
                 float* __restrict__ vsg, int* __restrict__ pmi) {
    __shared__ float tile[64][132];
    __shared__ float vsL[256];
    const int tid = threadIdx.x;
    const int bx  = blockIdx.x;
    const float* ksum = sums + NB * NL;
    const float* vsum = sums + 2 * NB * NL;
    if (bx < 256) {
        const int h = bx >> 4, jt = bx & 15;
        char* hiT = (char*)kPhi + (size_t)(h * 16 + jt) * 8192;
        char* loT = (char*)kPlo + (size_t)(h * 16 + jt) * 8192;
        const int row = tid >> 2;
        const int s0  = (tid & 3) * 16;
        const float* src = k_w + ((size_t)(h * NL + jt * 64 + row)) * HD + s0;
#pragma unroll
        for (int t = 0; t < 4; ++t) {
            float4 x = reinterpret_cast<const float4*>(src)[t];
            unsigned short h0, h1, h2, h3, l0, l1, l2, l3;
            bfsplit(x.x, h0, l0); bfsplit(x.y, h1, l1);
            bfsplit(x.z, h2, l2); bfsplit(x.w, h3, l3);
            int off = (row * 128 + (s0 + 4 * t) * 2) ^ ((row & 7) << 4);
            *(uint2*)(hiT + off) = make_uint2(pk2(h0, h1), pk2(h2, h3));
            *(uint2*)(loT + off) = make_uint2(pk2(l0, l1), pk2(l2, l3));
        }
    } else if (bx < 512) {
        const int h = (bx - 256) >> 4, jt = (bx - 256) & 15;
#pragma unroll
        for (int t = 0; t < 4; ++t) {
            int id = tid + 256 * t;
            int j = id >> 4, t4 = (id & 15) * 4;
            *(float4*)&tile[j][t4] =
                *(const float4*)(v_w + ((size_t)(h * NL + jt * 64 + j)) * HD + t4);
        }
        vsL[tid] = vsum[(tid >> 6) * NL + jt * 64 + (tid & 63)];
        __syncthreads();
        char* vT_ = (char*)vP + (size_t)(h * 16 + jt) * 8192;
        const int trow = tid >> 2;
        const int jq   = (tid & 3) * 16;
#pragma unroll
        for (int q = 0; q < 4; ++q) {
            int j4 = jq + 4 * q;
            uint2 u;
            u.x = pk2(f2bf(tile[j4 + 0][trow]), f2bf(tile[j4 + 1][trow]));
            u.y = pk2(f2bf(tile[j4 + 2][trow]), f2bf(tile[j4 + 3][trow]));
            int off = (trow * 128 + j4 * 2) ^ ((trow & 7) << 4);
            *(uint2*)(vT_ + off) = u;
        }
        if (jt >= 1) {
            const int b = tid >> 6, t = tid & 63;
            float a = 0.f;
#pragma unroll 16
            for (int j = 0; j < 64; ++j)
                a = fmaf(vsL[b * 64 + j], tile[j][t], a);
            S[(((size_t)h * 16 + jt) * 4 + b) * 64 + t] = a;
        }
    } else if (bx < 640) {
        const int bxo = bx - 512;
        const int ot = bxo >> 4, kt = bxo & 15;
#pragma unroll
        for (int t = 0; t < 8; ++t) {
            int id = tid + 256 * t;
            int c = id >> 5, o4 = (id & 31) * 4;
            *(float4*)&tile[c][o4] =
                *(const float4*)(o_w + ((size_t)(kt * 64 + c)) * ND + ot * 128 + o4);
        }
        __syncthreads();
        char* bT = (char*)BP + (size_t)(ot * 16 + kt) * 16384;
#pragma unroll
        for (int t = 0; t < 8; ++t) {
            int id = tid + 256 * t;
            int ol = id >> 4, c4 = (id & 15) * 4;
            uint2 u;
            u.x = pk2(f2bf(tile[c4 + 0][ol]), f2bf(tile[c4 + 1][ol]));
            u.y = pk2(f2bf(tile[c4 + 2][ol]), f2bf(tile[c4 + 3][ol]));
            int off = (ol * 128 + c4 * 2) ^ ((ol & 7) << 4);
            *(uint2*)(bT + off) = u;
        }
    } else {
        // per-j softmax operand tables
        const int e = (bx - 640) * 256 + tid;   // 0..4095
        const int j = e >> 2, b = e & 3;
        ksg[e] = ksum[b * NL + j] * (LOG2E * 0.25f);
        vsg[e] = vsum[b * NL + j];
        if (b == 0)
            pmi[j] = pad[j] | (pad[NL + j] << 1) | (pad[2 * NL + j] << 2) |
                     (pad[3 * NL + j] << 3);
    }
}

// ---------------------------------------------------------------------------
// Kernel 3: fused attn with causal-tile skip.
// Q fragments in registers; ks/vs/pad from per-j global tables; G as
// mfma(A=K, B=Q) with split accumulator chains.
// ---------------------------------------------------------------------------
__global__ __launch_bounds__(512, 4)
void attn_kernel(const float* __restrict__ q_w, const float* __restrict__ sums,
                 const unsigned short* __restrict__ kPhi,
                 const unsigned short* __restrict__ kPlo,
                 const unsigned short* __restrict__ vP,
                 const float* __restrict__ ksg, const float* __restrict__ vsg,
                 const int* __restrict__ pmi, const float* __restrict__ S,
                 unsigned short* __restrict__ AP) {
    __shared__ __align__(16) unsigned short kHi[2][4096], kLo[2][4096], vTl[2][4096];
    __shared__ __align__(16) unsigned short wlds[8192];

    const float* qsum = sums;

    const int wid = blockIdx.x;
    const int gq  = wid >> 4;
    const int h   = wid & 15;
    const int itp = (gq < 16) ? (2 * gq) : (63 - 2 * gq);  // work-balanced remap
    const int it0 = itp * 32;
    const int cut = (it0 >> 6) + 1;

    const int tid  = threadIdx.x;
    const int lane = tid & 63;
    const int w    = tid >> 6;
    const int l15  = lane & 15;
    const int kb   = (lane >> 4) * 16;

    const int gmi = (w & 1) * 16;     // i-frag base (B operand)
    const int gnj = (w >> 1) * 16;    // j-frag base (A operand)
    const int pb  = w >> 1;
    const int pmh = (w & 1) * 16;

    // ---- Q fragment in registers (lane-static rows), hi/lo split ----
    const int i_sm = gmi + l15;
    const int ig   = it0 + i_sm;
    bf16x8 qHiF[2], qLoF[2];
    {
        const float* qp = q_w + ((size_t)(h * NL + ig)) * HD + (lane >> 4) * 8;
#pragma unroll
        for (int ks = 0; ks < 2; ++ks) {
            float f[8];
            *(float4*)&f[0] = *(const float4*)(qp + ks * 32);
            *(float4*)&f[4] = *(const float4*)(qp + ks * 32 + 4);
            unsigned short hh[8], ll[8];
#pragma unroll
            for (int e = 0; e < 8; ++e) bfsplit(f[e], hh[e], ll[e]);
            uint4 H = make_uint4(pk2(hh[0], hh[1]), pk2(hh[2], hh[3]),
                                 pk2(hh[4], hh[5]), pk2(hh[6], hh[7]));
            uint4 L = make_uint4(pk2(ll[0], ll[1]), pk2(ll[2], ll[3]),
                                 pk2(ll[4], ll[5]), pk2(ll[6], ll[7]));
            qHiF[ks] = __builtin_bit_cast(bf16x8, H);
            qLoF[ks] = __builtin_bit_cast(bf16x8, L);
        }
    }
    float4 qsv;
    qsv.x = qsum[0 * NL + ig]; qsv.y = qsum[1 * NL + ig];
    qsv.z = qsum[2 * NL + ig]; qsv.w = qsum[3 * NL + ig];

    auto stage = [&](int buf, int jt) {
        const size_t tb = (size_t)(h * 16 + jt) * 8192 + tid * 16;
        gload16((char*)kHi[buf] + tid * 16, (const char*)kPhi + tb);
        gload16((char*)kLo[buf] + tid * 16, (const char*)kPlo + tb);
        gload16((char*)vTl[buf] + tid * 16, (const char*)vP + tb);
    };

    f32x4 accP[4];
#pragma unroll
    for (int n = 0; n < 4; ++n) accP[n] = (f32x4){0.f, 0.f, 0.f, 0.f};

    stage(0, 0);
    __syncthreads();
    int cur = 0;

    const int jb_sm = gnj + (lane >> 4) * 4;
    const int woff  = (i_sm * 128 + jb_sm * 2) ^ ((i_sm & 7) << 4);

    for (int jt = 0; jt < cut; ++jt) {
        const int j0 = jt * 64;
        if (jt + 1 < cut) stage(cur ^ 1, jt + 1);

        // ---- G: one 16x16 fragment per wave, bf16x3, split chains ----
        f32x4 gA = (f32x4){0.f, 0.f, 0.f, 0.f};
        f32x4 gB = (f32x4){0.f, 0.f, 0.f, 0.f};
#pragma unroll
        for (int ks = 0; ks < 2; ++ks) {
            const int arow = gnj + l15;
            const int aoff = (arow * 128 + ks * 64 + kb) ^ ((arow & 7) << 4);
            bf16x8 kHiF = __builtin_bit_cast(bf16x8, *(const uint4*)((const char*)kHi[cur] + aoff));
            bf16x8 kLoF = __builtin_bit_cast(bf16x8, *(const uint4*)((const char*)kLo[cur] + aoff));
            gA = __builtin_amdgcn_mfma_f32_16x16x32_bf16(kHiF, qHiF[ks], gA, 0, 0, 0);
            gA = __builtin_amdgcn_mfma_f32_16x16x32_bf16(kLoF, qHiF[ks], gA, 0, 0, 0);
            gB = __builtin_amdgcn_mfma_f32_16x16x32_bf16(kHiF, qLoF[ks], gB, 0, 0, 0);
        }
        const f32x4 g = gA + gB;

        // ---- per-lane 4-batch softmax (exp2 domain); row r = j, col = i ----
        {
            float wv[4][4];   // [r][b]
#pragma unroll
            for (int r = 0; r < 4; ++r) {
                const int jg = j0 + jb_sm + r;
                const float4 ksv = *(const float4*)(ksg + 4 * jg);
                const float4 vsv = *(const float4*)(vsg + 4 * jg);
                const int pm = pmi[jg] | ((jg > ig) ? 15 : 0);
                const float gr = g[r];
                const float sb0 = (pm & 1) ? FMIN_F32 : qsv.x * ksv.x * gr;
                const float sb1 = (pm & 2) ? FMIN_F32 : qsv.y * ksv.y * gr;
                const float sb2 = (pm & 4) ? FMIN_F32 : qsv.z * ksv.z * gr;
                const float sb3 = (pm & 8) ? FMIN_F32 : qsv.w * ksv.w * gr;
                const float mx = fmaxf(fmaxf(sb0, sb1), fmaxf(sb2, sb3));
                const float e0 = __builtin_amdgcn_exp2f(sb0 - mx);
                const float e1 = __builtin_amdgcn_exp2f(sb1 - mx);
                const float e2 = __builtin_amdgcn_exp2f(sb2 - mx);
                const float e3 = __builtin_amdgcn_exp2f(sb3 - mx);
                const float inv = __builtin_amdgcn_rcpf((e0 + e1) + (e2 + e3));
                wv[r][0] = e0 * inv * vsv.x;
                wv[r][1] = e1 * inv * vsv.y;
                wv[r][2] = e2 * inv * vsv.z;
                wv[r][3] = e3 * inv * vsv.w;
            }
#pragma unroll
            for (int b = 0; b < 4; ++b) {
                uint2 p;
                p.x = pk2(f2bf(wv[0][b]), f2bf(wv[1][b]));
                p.y = pk2(f2bf(wv[2][b]), f2bf(wv[3][b]));
                *(uint2*)((char*)wlds + b * 4096 + woff) = p;
            }
        }
        // ---- barrier A: wlds visible; in-flight stages may continue ----
        asm volatile("s_waitcnt lgkmcnt(0)" ::: "memory");
        __builtin_amdgcn_s_barrier();
        __builtin_amdgcn_sched_barrier(0);

        // ---- PV: wave (pb, pmh): 16 i-rows x 64 t for batch pb ----
        __builtin_amdgcn_s_setprio(1);
#pragma unroll
        for (int ks = 0; ks < 2; ++ks) {
            const int arow = pmh + l15;
            const int aoff = pb * 4096 + ((arow * 128 + ks * 64 + kb) ^ ((arow & 7) << 4));
            bf16x8 aF = __builtin_bit_cast(bf16x8, *(const uint4*)((const char*)wlds + aoff));
#pragma unroll
            for (int n = 0; n < 4; ++n) {
                const int vrow = n * 16 + l15;
                const int voff = (vrow * 128 + ks * 64 + kb) ^ ((vrow & 7) << 4);
                bf16x8 bF = __builtin_bit_cast(bf16x8, *(const uint4*)((const char*)vTl[cur] + voff));
                accP[n] = __builtin_amdgcn_mfma_f32_16x16x32_bf16(aF, bF, accP[n], 0, 0, 0);
            }
        }
        __builtin_amdgcn_s_setprio(0);
        __syncthreads();   // full drain: stages landed, PV/wlds reads done
        cur ^= 1;
    }

    // ---- add fully-masked causal suffix: 0.25 * sum_{jt>=cut} S[h][jt][pb][t] ----
    if (cut < 16) {
        float sv[4] = {0.f, 0.f, 0.f, 0.f};
        for (int jt = cut; jt < 16; ++jt) {
            const float* sp = S + (((size_t)h * 16 + jt) * 4 + pb) * 64;
#pragma unroll
            for (int n = 0; n < 4; ++n) sv[n] += sp[n * 16 + l15];
        }
#pragma unroll
        for (int n = 0; n < 4; ++n) {
            const float s4v = 0.25f * sv[n];
#pragma unroll
            for (int r = 0; r < 4; ++r) accP[n][r] += s4v;
        }
    }

    // ---- store AP tiles (pre-swizzled out-GEMM A layout, bf16) ----
    {
        const int ib = (it0 + pmh) >> 4;
        char* tbase = (char*)AP + (size_t)((pb * 16 + h) * 16) * 8192;
#pragma unroll
        for (int n = 0; n < 4; ++n)
#pragma unroll
            for (int r = 0; r < 4; ++r) {
                int kt = (lane >> 4) * 4 + r;
                int tt = n * 16 + l15;
                int off = (ib * 128 + tt * 2) ^ ((ib & 7) << 4);
                *(unsigned short*)(tbase + (size_t)kt * 8192 + off) = f2bf(accP[n][r]);
            }
    }
}

// ---------------------------------------------------------------------------
// Kernel 4: out(4096x1024) = AP @ BP. 64x128 tiles, grid (8,64), 256 threads.
// 3 LDS buffers, stage 2 ahead, counted vmcnt(6); setprio around MFMA.
// ---------------------------------------------------------------------------
__global__ __launch_bounds__(256, 2)
void outgemm_kernel(const unsigned short* __restrict__ AP,
                    const unsigned short* __restrict__ BP,
                    float* __restrict__ out) {
    __shared__ __align__(16) unsigned short aL[3][4096];
    __shared__ __align__(16) unsigned short bL[3][8192];
    const int ox = blockIdx.x;
    const int my = blockIdx.y;
    const int tid  = threadIdx.x;
    const int lane = tid & 63;
    const int w    = tid >> 6;
    const int wr = (w & 1) * 32;
    const int wc = (w >> 1) * 64;
    const int l15  = lane & 15;
    const int kseg = (lane >> 4) * 16;

    f32x4 acc[2][4];
#pragma unroll
    for (int m = 0; m < 2; ++m)
#pragma unroll
        for (int n = 0; n < 4; ++n) acc[m][n] = (f32x4){0.f, 0.f, 0.f, 0.f};

    auto stage = [&](int buf, int kt) {
        const char* at = (const char*)AP + (size_t)(my * 16 + kt) * 8192;
        const char* bt = (const char*)BP + (size_t)(ox * 16 + kt) * 16384;
        gload16((char*)aL[buf] + tid * 16, at + tid * 16);
        gload16((char*)aL[buf] + 4096 + tid * 16, at + 4096 + tid * 16);
#pragma unroll
        for (int r = 0; r < 4; ++r)
            gload16((char*)bL[buf] + r * 4096 + tid * 16, bt + r * 4096 + tid * 16);
    };

    auto compute = [&](int cb) {
        __builtin_amdgcn_s_setprio(1);
#pragma unroll
        for (int ks = 0; ks < 2; ++ks) {
            bf16x8 aF[2], bF[4];
#pragma unroll
            for (int m = 0; m < 2; ++m) {
                int row = wr + m * 16 + l15;
                int off = (row * 128 + ks * 64 + kseg) ^ ((row & 7) << 4);
                aF[m] = __builtin_bit_cast(bf16x8, *(const uint4*)((const char*)aL[cb] + off));
            }
#pragma unroll
            for (int n = 0; n < 4; ++n) {
                int row = wc + n * 16 + l15;
                int off = (row * 128 + ks * 64 + kseg) ^ ((row & 7) << 4);
                bF[n] = __builtin_bit_cast(bf16x8, *(const uint4*)((const char*)bL[cb] + off));
            }
#pragma unroll
            for (int m = 0; m < 2; ++m)
#pragma unroll
                for (int n = 0; n < 4; ++n)
                    acc[m][n] = __builtin_amdgcn_mfma_f32_16x16x32_bf16(
                        aF[m], bF[n], acc[m][n], 0, 0, 0);
        }
        __builtin_amdgcn_s_setprio(0);
    };

    stage(0, 0);
    stage(1, 1);
    for (int kt = 0; kt < 15; ++kt) {
        asm volatile("s_waitcnt vmcnt(6)" ::: "memory");
        __builtin_amdgcn_s_barrier();
        __builtin_amdgcn_sched_barrier(0);
        if (kt + 2 < 16) stage((kt + 2) % 3, kt + 2);
        compute(kt % 3);
    }
    asm volatile("s_waitcnt vmcnt(0)" ::: "memory");
    __builtin_amdgcn_s_barrier();
    __builtin_amdgcn_sched_barrier(0);
    compute(15 % 3);

#pragma unroll
    for (int m = 0; m < 2; ++m)
#pragma unroll
        for (int n = 0; n < 4; ++n)
#pragma unroll
            for (int r = 0; r < 4; ++r) {
                int row = my * 64 + wr + m * 16 + (lane >> 4) * 4 + r;
                int col = ox * 128 + wc + n * 16 + l15;
                out[(size_t)row * ND + col] = acc[m][n][r];
            }
}

// ---------------------------------------------------------------------------
extern "C" void kernel_launch(void* const* d_in, const int* in_sizes, int n_in,
                              void* d_out, int out_size, void* d_ws, size_t ws_size,
                              hipStream_t stream) {
    const float* query = (const float*)d_in[0];
    const float* key   = (const float*)d_in[1];
    const float* value = (const float*)d_in[2];
    const int*   pad   = (const int*)d_in[3];
    const float* q_w   = (const float*)d_in[4];
    const float* k_w   = (const float*)d_in[5];
    const float* v_w   = (const float*)d_in[6];
    const float* o_w   = (const float*)d_in[7];
    float* out = (float*)d_out;

    char* W = (char*)d_ws;
    float*          sums = (float*)W;                         // 48 KB
    unsigned short* kPhi = (unsigned short*)(W + 49152);      // 2 MB
    unsigned short* kPlo = (unsigned short*)(W + 2146304);    // 2 MB
    unsigned short* vP   = (unsigned short*)(W + 4243456);    // 2 MB
    unsigned short* BP   = (unsigned short*)(W + 6340608);    // 2 MB
    unsigned short* AP   = (unsigned short*)(W + 8437760);    // 8 MB
    float*          ksg  = (float*)(W + 16826368);            // 16 KB
    float*          vsg  = (float*)(W + 16842752);            // 16 KB
    int*            pmi  = (int*)(W + 16859136);              // 4 KB

    float* S = out;   // 256 KB scratch in d_out; overwritten by outgemm

    rowsum_kernel<<<3 * (NB * NL) / 4, 256, 0, stream>>>(query, key, value, sums);

    prep_kernel<<<656, 256, 0, stream>>>(k_w, v_w, o_w, sums, pad,
                                         kPhi, kPlo, vP, BP, S, ksg, vsg, pmi);

    attn_kernel<<<512, 512, 0, stream>>>(q_w, sums, kPhi, kPlo, vP,
                                         ksg, vsg, pmi, S, AP);

    dim3 gg(8, 64);
    outgemm_kernel<<<gg, 256, 0, stream>>>(AP, BP, out);
}

// Round 10
// 69.946 us; speedup vs baseline: 1.0819x; 1.0819x over previous
//
#include <hip/hip_runtime.h>
#include <hip/hip_bf16.h>

#define NB 4
#define NL 1024
#define NH 16
#define ND 1024
#define HD 64
#define FMIN_F32 (-3.4028234663852886e38f)
#define LOG2E 1.4426950408889634f

typedef __bf16 bf16x8 __attribute__((ext_vector_type(8)));
typedef float f32x4 __attribute__((ext_vector_type(4)));
typedef unsigned int u32;

static __device__ inline unsigned short f2bf(float f) {
    __hip_bfloat16 h = __float2bfloat16(f);
    return __builtin_bit_cast(unsigned short, h);
}

// split f32 into bf16 hi + bf16 lo (x ~= hi + lo, error ~2^-18 rel)
static __device__ inline void bfsplit(float x, unsigned short& hi, unsigned short& lo) {
    unsigned u = __builtin_bit_cast(unsigned, x);
    unsigned r = (u + 0x7FFFu + ((u >> 16) & 1u)) >> 16;
    hi = (unsigned short)r;
    float hf = __builtin_bit_cast(float, r << 16);
    lo = f2bf(x - hf);
}

static __device__ inline u32 pk2(unsigned short a, unsigned short b) {
    return (u32)a | ((u32)b << 16);
}

// async global->LDS, 16B per lane. LDS dest = firstlane(lds)+lane*16.
static __device__ __forceinline__ void gload16(void* lds, const void* g) {
    __builtin_amdgcn_global_load_lds(
        (const __attribute__((address_space(1))) u32*)g,
        (__attribute__((address_space(3))) u32*)lds, 16, 0, 0);
}

// ---------------------------------------------------------------------------
// Kernel 1: row sums of query/key/value.
// ---------------------------------------------------------------------------
__global__ __launch_bounds__(256)
void rowsum_kernel(const float* __restrict__ q, const float* __restrict__ k,
                   const float* __restrict__ v, float* __restrict__ out) {
    int gw   = blockIdx.x * 4 + (threadIdx.x >> 6);
    int lane = threadIdx.x & 63;
    int tensor = gw >> 12;
    int row    = gw & 4095;
    const float* src = tensor == 0 ? q : (tensor == 1 ? k : v);
    const float* p = src + (size_t)row * ND;
    float s = 0.f;
#pragma unroll
    for (int t = 0; t < 4; ++t) {
        float4 x = *reinterpret_cast<const float4*>(p + t * 256 + lane * 4);
        s += (x.x + x.y) + (x.z + x.w);
    }
#pragma unroll
    for (int off = 32; off; off >>= 1) s += __shfl_xor(s, off);
    if (lane == 0) out[tensor * (NB * NL) + row] = s;
}

// ---------------------------------------------------------------------------
// Kernel 2: prep — pre-swizzled operand tiles + per-tile S sums.
//  [0,256):   k_w -> kPhi/kPlo  [h][jt] 8KB tiles, (j_local, s)
//  [256,512): v_w -> vP [h][jt] 8KB tiles (t, j_local) + S[h][jt][b][t]
//  [512,640): o_w -> BP [ot][kt] 16KB tiles (o, c)
// ---------------------------------------------------------------------------
__global__ __launch_bounds__(256)
void prep_kernel(const float* __restrict__ k_w, const float* __restrict__ v_w,
                 const float* __restrict__ o_w, const float* __restrict__ sums,
                 unsigned short* __restrict__ kPhi, unsigned short* __restrict__ kPlo,
                 unsigned short* __restrict__ vP, unsigned short* __restrict__ BP,
                 float* __restrict__ S) {
    __shared__ float tile[64][132];
    __shared__ float vsL[256];
    const int tid = threadIdx.x;
    const int bx  = blockIdx.x;
    const float* vsum = sums + 2 * NB * NL;
    if (bx < 256) {
        const int h = bx >> 4, jt = bx & 15;
        char* hiT = (char*)kPhi + (size_t)(h * 16 + jt) * 8192;
        char* loT = (char*)kPlo + (size_t)(h * 16 + jt) * 8192;
        const int row = tid >> 2;
        const int s0  = (tid & 3) * 16;
        const float* src = k_w + ((size_t)(h * NL + jt * 64 + row)) * HD + s0;
#pragma unroll
        for (int t = 0; t < 4; ++t) {
            float4 x = reinterpret_cast<const float4*>(src)[t];
            unsigned short h0, h1, h2, h3, l0, l1, l2, l3;
            bfsplit(x.x, h0, l0); bfsplit(x.y, h1, l1);
            bfsplit(x.z, h2, l2); bfsplit(x.w, h3, l3);
            int off = (row * 128 + (s0 + 4 * t) * 2) ^ ((row & 7) << 4);
            *(uint2*)(hiT + off) = make_uint2(pk2(h0, h1), pk2(h2, h3));
            *(uint2*)(loT + off) = make_uint2(pk2(l0, l1), pk2(l2, l3));
        }
    } else if (bx < 512) {
        const int h = (bx - 256) >> 4, jt = (bx - 256) & 15;
#pragma unroll
        for (int t = 0; t < 4; ++t) {
            int id = tid + 256 * t;
            int j = id >> 4, t4 = (id & 15) * 4;
            *(float4*)&tile[j][t4] =
                *(const float4*)(v_w + ((size_t)(h * NL + jt * 64 + j)) * HD + t4);
        }
        vsL[tid] = vsum[(tid >> 6) * NL + jt * 64 + (tid & 63)];
        __syncthreads();
        char* vT_ = (char*)vP + (size_t)(h * 16 + jt) * 8192;
        const int trow = tid >> 2;
        const int jq   = (tid & 3) * 16;
#pragma unroll
        for (int q = 0; q < 4; ++q) {
            int j4 = jq + 4 * q;
            uint2 u;
            u.x = pk2(f2bf(tile[j4 + 0][trow]), f2bf(tile[j4 + 1][trow]));
            u.y = pk2(f2bf(tile[j4 + 2][trow]), f2bf(tile[j4 + 3][trow]));
            int off = (trow * 128 + j4 * 2) ^ ((trow & 7) << 4);
            *(uint2*)(vT_ + off) = u;
        }
        if (jt >= 1) {
            const int b = tid >> 6, t = tid & 63;
            float a = 0.f;
#pragma unroll 16
            for (int j = 0; j < 64; ++j)
                a = fmaf(vsL[b * 64 + j], tile[j][t], a);
            S[(((size_t)h * 16 + jt) * 4 + b) * 64 + t] = a;
        }
    } else {
        const int bxo = bx - 512;
        const int ot = bxo >> 4, kt = bxo & 15;
#pragma unroll
        for (int t = 0; t < 8; ++t) {
            int id = tid + 256 * t;
            int c = id >> 5, o4 = (id & 31) * 4;
            *(float4*)&tile[c][o4] =
                *(const float4*)(o_w + ((size_t)(kt * 64 + c)) * ND + ot * 128 + o4);
        }
        __syncthreads();
        char* bT = (char*)BP + (size_t)(ot * 16 + kt) * 16384;
#pragma unroll
        for (int t = 0; t < 8; ++t) {
            int id = tid + 256 * t;
            int ol = id >> 4, c4 = (id & 15) * 4;
            uint2 u;
            u.x = pk2(f2bf(tile[c4 + 0][ol]), f2bf(tile[c4 + 1][ol]));
            u.y = pk2(f2bf(tile[c4 + 2][ol]), f2bf(tile[c4 + 3][ol]));
            int off = (ol * 128 + c4 * 2) ^ ((ol & 7) << 4);
            *(uint2*)(bT + off) = u;
        }
    }
}

// ---------------------------------------------------------------------------
// Kernel 3: fused attn with causal-tile skip (round-8 structure).
// G as mfma(A=K, B=Q) with split accumulator chains; LDS-staged softmax
// operands; lgkm-only barrier A + full barrier B; setprio around PV.
// ---------------------------------------------------------------------------
__global__ __launch_bounds__(512, 4)
void attn_kernel(const float* __restrict__ q_w, const int* __restrict__ pad,
                 const float* __restrict__ sums,
                 const unsigned short* __restrict__ kPhi,
                 const unsigned short* __restrict__ kPlo,
                 const unsigned short* __restrict__ vP,
                 const float* __restrict__ S,
                 unsigned short* __restrict__ AP) {
    __shared__ __align__(16) unsigned short kHi[2][4096], kLo[2][4096], vTl[2][4096];
    __shared__ __align__(16) unsigned short qHi[2048], qLo[2048];
    __shared__ __align__(16) unsigned short wlds[8192];
    __shared__ __align__(16) float qs4[128];
    __shared__ __align__(16) float ks4[2][256];
    __shared__ __align__(16) float vs4[2][256];
    __shared__ __align__(16) int   pm4[2][256];

    const float* qsum = sums;
    const float* ksum = sums + NB * NL;
    const float* vsum = sums + 2 * NB * NL;

    const int wid = blockIdx.x;
    const int gq  = wid >> 4;
    const int h   = wid & 15;
    const int itp = (gq < 16) ? (2 * gq) : (63 - 2 * gq);  // work-balanced remap
    const int it0 = itp * 32;
    const int cut = (it0 >> 6) + 1;

    const int tid  = threadIdx.x;
    const int lane = tid & 63;
    const int w    = tid >> 6;
    const int l15  = lane & 15;
    const int kb   = (lane >> 4) * 16;

    // ---- stage q tile (f32 -> bf16 hi/lo, swizzled), once ----
    {
        int row = tid >> 4;
        int s4  = (tid & 15) * 4;
        float4 x = *(const float4*)(q_w + ((size_t)(h * NL + it0 + row)) * HD + s4);
        unsigned short h0, h1, h2, h3, l0, l1, l2, l3;
        bfsplit(x.x, h0, l0); bfsplit(x.y, h1, l1);
        bfsplit(x.z, h2, l2); bfsplit(x.w, h3, l3);
        int off = (row * 128 + s4 * 2) ^ ((row & 7) << 4);
        *(uint2*)((char*)qHi + off) = make_uint2(pk2(h0, h1), pk2(h2, h3));
        *(uint2*)((char*)qLo + off) = make_uint2(pk2(l0, l1), pk2(l2, l3));
    }
    if (tid < 128) {
        int b = tid >> 5, i = tid & 31;
        qs4[i * 4 + b] = qsum[b * NL + it0 + i];
    }

    auto stage = [&](int buf, int jt) {
        const size_t tb = (size_t)(h * 16 + jt) * 8192 + tid * 16;
        gload16((char*)kHi[buf] + tid * 16, (const char*)kPhi + tb);
        gload16((char*)kLo[buf] + tid * 16, (const char*)kPlo + tb);
        gload16((char*)vTl[buf] + tid * 16, (const char*)vP + tb);
        if (tid < 256) {
            int b = tid >> 6, jj = tid & 63;
            ks4[buf][jj * 4 + b] = ksum[b * NL + jt * 64 + jj] * (LOG2E * 0.25f);
            vs4[buf][jj * 4 + b] = vsum[b * NL + jt * 64 + jj];
            pm4[buf][jj * 4 + b] = pad[b * NL + jt * 64 + jj];
        }
    };

    const int gmi = (w & 1) * 16;     // i-frag base (B operand)
    const int gnj = (w >> 1) * 16;    // j-frag base (A operand)
    const int pb  = w >> 1;
    const int pmh = (w & 1) * 16;

    f32x4 accP[4];
#pragma unroll
    for (int n = 0; n < 4; ++n) accP[n] = (f32x4){0.f, 0.f, 0.f, 0.f};

    stage(0, 0);
    __syncthreads();
    int cur = 0;

    // per-thread softmax geometry (fixed i, 4 consecutive j per tile)
    const int i_sm  = gmi + l15;
    const int ig    = it0 + i_sm;
    const int jb_sm = gnj + (lane >> 4) * 4;
    const float4 qsv = *(const float4*)&qs4[i_sm * 4];
    const int woff = (i_sm * 128 + jb_sm * 2) ^ ((i_sm & 7) << 4);

    for (int jt = 0; jt < cut; ++jt) {
        const int j0 = jt * 64;
        if (jt + 1 < cut) stage(cur ^ 1, jt + 1);

        // ---- G: one 16x16 fragment per wave, bf16x3, split chains ----
        f32x4 gA = (f32x4){0.f, 0.f, 0.f, 0.f};
        f32x4 gB = (f32x4){0.f, 0.f, 0.f, 0.f};
#pragma unroll
        for (int ks = 0; ks < 2; ++ks) {
            const int arow = gnj + l15;   // K rows (A)
            const int brow = gmi + l15;   // Q rows (B)
            const int aoff = (arow * 128 + ks * 64 + kb) ^ ((arow & 7) << 4);
            const int boff = (brow * 128 + ks * 64 + kb) ^ ((brow & 7) << 4);
            bf16x8 kHiF = __builtin_bit_cast(bf16x8, *(const uint4*)((const char*)kHi[cur] + aoff));
            bf16x8 kLoF = __builtin_bit_cast(bf16x8, *(const uint4*)((const char*)kLo[cur] + aoff));
            bf16x8 qHiF = __builtin_bit_cast(bf16x8, *(const uint4*)((const char*)qHi + boff));
            bf16x8 qLoF = __builtin_bit_cast(bf16x8, *(const uint4*)((const char*)qLo + boff));
            gA = __builtin_amdgcn_mfma_f32_16x16x32_bf16(kHiF, qHiF, gA, 0, 0, 0);
            gA = __builtin_amdgcn_mfma_f32_16x16x32_bf16(kLoF, qHiF, gA, 0, 0, 0);
            gB = __builtin_amdgcn_mfma_f32_16x16x32_bf16(kHiF, qLoF, gB, 0, 0, 0);
        }
        const f32x4 g = gA + gB;

        // ---- per-lane 4-batch softmax (exp2 domain); C row r = j, col = i ----
        {
            float wv[4][4];   // [r][b]
#pragma unroll
            for (int r = 0; r < 4; ++r) {
                const int j  = jb_sm + r;
                const int jg = j0 + j;
                const float4 ksv = *(const float4*)&ks4[cur][j * 4];
                const float4 vsv = *(const float4*)&vs4[cur][j * 4];
                const int4   pmv = *(const int4*)&pm4[cur][j * 4];
                const float gr = g[r];
                const bool causal = jg > ig;
                const float sb0 = (causal || pmv.x) ? FMIN_F32 : qsv.x * ksv.x * gr;
                const float sb1 = (causal || pmv.y) ? FMIN_F32 : qsv.y * ksv.y * gr;
                const float sb2 = (causal || pmv.z) ? FMIN_F32 : qsv.z * ksv.z * gr;
                const float sb3 = (causal || pmv.w) ? FMIN_F32 : qsv.w * ksv.w * gr;
                const float mx = fmaxf(fmaxf(sb0, sb1), fmaxf(sb2, sb3));
                const float e0 = __builtin_amdgcn_exp2f(sb0 - mx);
                const float e1 = __builtin_amdgcn_exp2f(sb1 - mx);
                const float e2 = __builtin_amdgcn_exp2f(sb2 - mx);
                const float e3 = __builtin_amdgcn_exp2f(sb3 - mx);
                const float inv = __builtin_amdgcn_rcpf((e0 + e1) + (e2 + e3));
                wv[r][0] = e0 * inv * vsv.x;
                wv[r][1] = e1 * inv * vsv.y;
                wv[r][2] = e2 * inv * vsv.z;
                wv[r][3] = e3 * inv * vsv.w;
            }
#pragma unroll
            for (int b = 0; b < 4; ++b) {
                uint2 p;
                p.x = pk2(f2bf(wv[0][b]), f2bf(wv[1][b]));
                p.y = pk2(f2bf(wv[2][b]), f2bf(wv[3][b]));
                *(uint2*)((char*)wlds + b * 4096 + woff) = p;
            }
        }
        // ---- barrier A: wlds visible; do NOT drain in-flight jt+1 stages ----
        asm volatile("s_waitcnt lgkmcnt(0)" ::: "memory");
        __builtin_amdgcn_s_barrier();
        __builtin_amdgcn_sched_barrier(0);

        // ---- PV: wave (pb, pmh): 16 i-rows x 64 t for batch pb ----
        __builtin_amdgcn_s_setprio(1);
#pragma unroll
        for (int ks = 0; ks < 2; ++ks) {
            const int arow = pmh + l15;
            const int aoff = pb * 4096 + ((arow * 128 + ks * 64 + kb) ^ ((arow & 7) << 4));
            bf16x8 aF = __builtin_bit_cast(bf16x8, *(const uint4*)((const char*)wlds + aoff));
#pragma unroll
            for (int n = 0; n < 4; ++n) {
                const int vrow = n * 16 + l15;
                const int voff = (vrow * 128 + ks * 64 + kb) ^ ((vrow & 7) << 4);
                bf16x8 bF = __builtin_bit_cast(bf16x8, *(const uint4*)((const char*)vTl[cur] + voff));
                accP[n] = __builtin_amdgcn_mfma_f32_16x16x32_bf16(aF, bF, accP[n], 0, 0, 0);
            }
        }
        __builtin_amdgcn_s_setprio(0);
        __syncthreads();   // full drain: stages landed, PV/wlds reads done
        cur ^= 1;
    }

    // ---- add fully-masked causal suffix: 0.25 * sum_{jt>=cut} S[h][jt][pb][t] ----
    if (cut < 16) {
        float sv[4] = {0.f, 0.f, 0.f, 0.f};
        for (int jt = cut; jt < 16; ++jt) {
            const float* sp = S + (((size_t)h * 16 + jt) * 4 + pb) * 64;
#pragma unroll
            for (int n = 0; n < 4; ++n) sv[n] += sp[n * 16 + l15];
        }
#pragma unroll
        for (int n = 0; n < 4; ++n) {
            const float s4v = 0.25f * sv[n];
#pragma unroll
            for (int r = 0; r < 4; ++r) accP[n][r] += s4v;
        }
    }

    // ---- store AP tiles (pre-swizzled out-GEMM A layout, bf16) ----
    {
        const int ib = (it0 + pmh) >> 4;
        char* tbase = (char*)AP + (size_t)((pb * 16 + h) * 16) * 8192;
#pragma unroll
        for (int n = 0; n < 4; ++n)
#pragma unroll
            for (int r = 0; r < 4; ++r) {
                int kt = (lane >> 4) * 4 + r;
                int tt = n * 16 + l15;
                int off = (ib * 128 + tt * 2) ^ ((ib & 7) << 4);
                *(unsigned short*)(tbase + (size_t)kt * 8192 + off) = f2bf(accP[n][r]);
            }
    }
}

// ---------------------------------------------------------------------------
// Kernel 4: out(4096x1024) = AP @ BP. 64x128 tiles, grid (8,64), 256 threads.
// 3 LDS buffers, stage 2 ahead, counted vmcnt(6); setprio around MFMA.
// ---------------------------------------------------------------------------
__global__ __launch_bounds__(256, 2)
void outgemm_kernel(const unsigned short* __restrict__ AP,
                    const unsigned short* __restrict__ BP,
                    float* __restrict__ out) {
    __shared__ __align__(16) unsigned short aL[3][4096];
    __shared__ __align__(16) unsigned short bL[3][8192];
    const int ox = blockIdx.x;
    const int my = blockIdx.y;
    const int tid  = threadIdx.x;
    const int lane = tid & 63;
    const int w    = tid >> 6;
    const int wr = (w & 1) * 32;
    const int wc = (w >> 1) * 64;
    const int l15  = lane & 15;
    const int kseg = (lane >> 4) * 16;

    f32x4 acc[2][4];
#pragma unroll
    for (int m = 0; m < 2; ++m)
#pragma unroll
        for (int n = 0; n < 4; ++n) acc[m][n] = (f32x4){0.f, 0.f, 0.f, 0.f};

    auto stage = [&](int buf, int kt) {
        const char* at = (const char*)AP + (size_t)(my * 16 + kt) * 8192;
        const char* bt = (const char*)BP + (size_t)(ox * 16 + kt) * 16384;
        gload16((char*)aL[buf] + tid * 16, at + tid * 16);
        gload16((char*)aL[buf] + 4096 + tid * 16, at + 4096 + tid * 16);
#pragma unroll
        for (int r = 0; r < 4; ++r)
            gload16((char*)bL[buf] + r * 4096 + tid * 16, bt + r * 4096 + tid * 16);
    };

    auto compute = [&](int cb) {
        __builtin_amdgcn_s_setprio(1);
#pragma unroll
        for (int ks = 0; ks < 2; ++ks) {
            bf16x8 aF[2], bF[4];
#pragma unroll
            for (int m = 0; m < 2; ++m) {
                int row = wr + m * 16 + l15;
                int off = (row * 128 + ks * 64 + kseg) ^ ((row & 7) << 4);
                aF[m] = __builtin_bit_cast(bf16x8, *(const uint4*)((const char*)aL[cb] + off));
            }
#pragma unroll
            for (int n = 0; n < 4; ++n) {
                int row = wc + n * 16 + l15;
                int off = (row * 128 + ks * 64 + kseg) ^ ((row & 7) << 4);
                bF[n] = __builtin_bit_cast(bf16x8, *(const uint4*)((const char*)bL[cb] + off));
            }
#pragma unroll
            for (int m = 0; m < 2; ++m)
#pragma unroll
                for (int n = 0; n < 4; ++n)
                    acc[m][n] = __builtin_amdgcn_mfma_f32_16x16x32_bf16(
                        aF[m], bF[n], acc[m][n], 0, 0, 0);
        }
        __builtin_amdgcn_s_setprio(0);
    };

    stage(0, 0);
    stage(1, 1);
    for (int kt = 0; kt < 15; ++kt) {
        asm volatile("s_waitcnt vmcnt(6)" ::: "memory");
        __builtin_amdgcn_s_barrier();
        __builtin_amdgcn_sched_barrier(0);
        if (kt + 2 < 16) stage((kt + 2) % 3, kt + 2);
        compute(kt % 3);
    }
    asm volatile("s_waitcnt vmcnt(0)" ::: "memory");
    __builtin_amdgcn_s_barrier();
    __builtin_amdgcn_sched_barrier(0);
    compute(15 % 3);

#pragma unroll
    for (int m = 0; m < 2; ++m)
#pragma unroll
        for (int n = 0; n < 4; ++n)
#pragma unroll
            for (int r = 0; r < 4; ++r) {
                int row = my * 64 + wr + m * 16 + (lane >> 4) * 4 + r;
                int col = ox * 128 + wc + n * 16 + l15;
                out[(size_t)row * ND + col] = acc[m][n][r];
            }
}

// ---------------------------------------------------------------------------
extern "C" void kernel_launch(void* const* d_in, const int* in_sizes, int n_in,
                              void* d_out, int out_size, void* d_ws, size_t ws_size,
                              hipStream_t stream) {
    const float* query = (const float*)d_in[0];
    const float* key   = (const float*)d_in[1];
    const float* value = (const float*)d_in[2];
    const int*   pad   = (const int*)d_in[3];
    const float* q_w   = (const float*)d_in[4];
    const float* k_w   = (const float*)d_in[5];
    const float* v_w   = (const float*)d_in[6];
    const float* o_w   = (const float*)d_in[7];
    float* out = (float*)d_out;

    char* W = (char*)d_ws;
    float*          sums = (float*)W;                        // 48 KB
    unsigned short* kPhi = (unsigned short*)(W + 49152);     // 2 MB
    unsigned short* kPlo = (unsigned short*)(W + 2146304);   // 2 MB
    unsigned short* vP   = (unsigned short*)(W + 4243456);   // 2 MB
    unsigned short* BP   = (unsigned short*)(W + 6340608);   // 2 MB
    unsigned short* AP   = (unsigned short*)(W + 8437760);   // 8 MB

    float* S = out;   // 256 KB scratch in d_out; overwritten by outgemm

    rowsum_kernel<<<3 * (NB * NL) / 4, 256, 0, stream>>>(query, key, value, sums);

    prep_kernel<<<640, 256, 0, stream>>>(k_w, v_w, o_w, sums, kPhi, kPlo, vP, BP, S);

    attn_kernel<<<512, 512, 0, stream>>>(q_w, pad, sums, kPhi, kPlo, vP, S, AP);

    dim3 gg(8, 64);
    outgemm_kernel<<<gg, 256, 0, stream>>>(AP, BP, out);
}